// Round 11
// baseline (456.562 us; speedup 1.0000x reference)
//
#include <hip/hip_runtime.h>

#define N_NODES 50000
#define N_EDGES 800000
#define DIN     128
#define H       96
#define K_EXP   8
#define L_LAYERS 4
#define C_OUT   40

#define GSZ 6250   // rows per XCD group = N_NODES/8

typedef _Float16 f16;
typedef f16 f16x2 __attribute__((ext_vector_type(2)));
typedef f16 f16x4 __attribute__((ext_vector_type(4)));
typedef f16 f16x8 __attribute__((ext_vector_type(8)));
typedef float f32x4 __attribute__((ext_vector_type(4)));

// ---------------- CSR build ----------------

__global__ __launch_bounds__(256) void count_p(const int* __restrict__ row,
                                               int* __restrict__ deg,
                                               int* __restrict__ p, int e) {
    int i = blockIdx.x * blockDim.x + threadIdx.x;
    if (i < e) p[i] = atomicAdd(&deg[row[i]], 1);
}

__global__ __launch_bounds__(1024) void scanA(const int* __restrict__ deg,
                                              int* __restrict__ rowptr,
                                              int* __restrict__ partial, int n) {
    __shared__ int wsum[16];
    int tid  = threadIdx.x;
    int lane = tid & 63, wid = tid >> 6;
    int idx = blockIdx.x * 1024 + tid;
    int v = (idx < n) ? deg[idx] : 0;
    int s = v;
    #pragma unroll
    for (int off = 1; off < 64; off <<= 1) {
        int t = __shfl_up(s, off, 64);
        if (lane >= off) s += t;
    }
    if (lane == 63) wsum[wid] = s;
    __syncthreads();
    if (wid == 0 && lane < 16) {
        int w = wsum[lane];
        #pragma unroll
        for (int off = 1; off < 16; off <<= 1) {
            int t = __shfl_up(w, off, 16);
            if (lane >= off) w += t;
        }
        wsum[lane] = w;
    }
    __syncthreads();
    int waveoff = (wid == 0) ? 0 : wsum[wid - 1];
    if (idx < n) rowptr[idx + 1] = waveoff + s;
    if (tid == 1023) partial[blockIdx.x] = waveoff + s;
}

// scanC with folded block-offset reduction: each block sums partial[0..bid-1]
__global__ __launch_bounds__(1024) void scanC(int* __restrict__ rowptr,
                                              const int* __restrict__ partial,
                                              int nb, int n) {
    __shared__ int boff_s;
    int tid = threadIdx.x;
    if (tid < 64) {
        int v = (tid < nb && tid < (int)blockIdx.x) ? partial[tid] : 0;
        #pragma unroll
        for (int off = 32; off >= 1; off >>= 1) v += __shfl_xor(v, off, 64);
        if (tid == 0) boff_s = v;
    }
    __syncthreads();
    int boff = boff_s;
    int idx = blockIdx.x * 1024 + tid;
    if (idx == 0) rowptr[0] = 0;
    if (idx < n) rowptr[idx + 1] += boff;
}

__global__ __launch_bounds__(256) void scatter_store_xcd(const int* __restrict__ row,
                                                         const int* __restrict__ col,
                                                         const int* __restrict__ p,
                                                         const int* __restrict__ rowptr,
                                                         int* __restrict__ csr, int e) {
    int g = blockIdx.x & 7;
    int rlo = g * GSZ, rhi = rlo + GSZ;
    int stride = (gridDim.x >> 3) * 256;
    for (int i = (blockIdx.x >> 3) * 256 + threadIdx.x; i < e; i += stride) {
        int r = row[i];
        if (r >= rlo && r < rhi)
            csr[rowptr[r] + p[i]] = col[i];
    }
}

// ---------------- weight conversion ----------------

#define CONV_TOT (L_LAYERS * K_EXP * H * H)   // 294912
#define FC0_TOT  (DIN * H)                    // 12288
#define FC1_TOT  (48 * H)                     // 4608

__global__ void convert_all(const float* __restrict__ conv_w,
                            const float* __restrict__ fc0_w,
                            const float* __restrict__ fc1_w,
                            f16* __restrict__ wfrag, f16* __restrict__ fc0t,
                            f16* __restrict__ fc1t) {
    int i = blockIdx.x * blockDim.x + threadIdx.x;
    if (i < CONV_TOT) {
        int o = i % H;
        int t = i / H;
        int d = t % H;
        int lk = t / H;
        int ct = o >> 4, lc = o & 15;
        int ks = d >> 5, quad = (d >> 3) & 3, j = d & 7;
        wfrag[(size_t)lk * 9216 + ct * 1536 + ks * 512 + (quad * 16 + lc) * 8 + j] =
            (f16)conv_w[i];
    } else if (i < CONV_TOT + FC0_TOT) {
        int j = i - CONV_TOT;      // j = d*96+o
        int o = j % H, d = j / H;
        fc0t[o * DIN + d] = (f16)fc0_w[j];
    } else if (i < CONV_TOT + FC0_TOT + FC1_TOT) {
        int j = i - CONV_TOT - FC0_TOT;  // target [o][d]
        int o = j / H, d = j % H;
        fc1t[j] = (o < C_OUT) ? (f16)fc1_w[d * C_OUT + o] : (f16)0.f;
    }
}

// ---------------- fused per-layer pre-pass: spmm + ctx softmax ----------------
// spmm: 64 rows/block, 16 lanes/group; each group interleaves FOUR independent
// rows (r, r+16, r+32, r+48) -> 4 gather loads in flight per lane (4x memory
// ILP on the latency-bound random gather). Lanes 0..11 own 8 feats each.

#define SPMM_BLOCKS ((N_NODES + 63) / 64)    // 782
#define CTX_BLOCKS  ((N_NODES + 255) / 256)  // 196

__global__ __launch_bounds__(256) void layer_pre(const f16* __restrict__ h16,
                                                 const int* __restrict__ rowptr,
                                                 const int* __restrict__ csr,
                                                 f16* __restrict__ hi16,
                                                 const float* __restrict__ cw,
                                                 const float* __restrict__ cb,
                                                 float* __restrict__ zt, int n) {
    __shared__ float ws[H * K_EXP];
    __shared__ float bs[K_EXP];
    int tid = threadIdx.x;
    if ((int)blockIdx.x < SPMM_BLOCKS) {
        int rb = blockIdx.x * 64 + (tid >> 4);
        int li = tid & 15;
        bool act = li < 12;
        int j[4], e[4];
        #pragma unroll
        for (int s = 0; s < 4; s++) {
            int r = rb + s * 16;
            if (r < n) { j[s] = rowptr[r]; e[s] = rowptr[r + 1]; }
            else       { j[s] = 0; e[s] = 0; }
        }
        float acc[4][8] = {};
        for (;;) {
            int m[4], mm = 0;
            #pragma unroll
            for (int s = 0; s < 4; s++) {
                m[s] = e[s] - j[s]; if (m[s] > 16) m[s] = 16;
                if (m[s] > mm) mm = m[s];
            }
            if (mm <= 0) break;
            int c[4];
            #pragma unroll
            for (int s = 0; s < 4; s++)
                c[s] = (li < m[s]) ? csr[j[s] + li] : 0;
            for (int t = 0; t < mm; t++) {
                int cc[4]; bool a[4];
                f16x8 v[4];
                #pragma unroll
                for (int s = 0; s < 4; s++) {
                    cc[s] = __shfl(c[s], t, 16);
                    a[s] = act && (t < m[s]);
                    v[s] = f16x8{};
                    if (a[s]) v[s] = *(const f16x8*)(h16 + (size_t)cc[s] * H + li * 8);
                }
                #pragma unroll
                for (int s = 0; s < 4; s++) {
                    if (a[s]) {
                        #pragma unroll
                        for (int q = 0; q < 8; q++) acc[s][q] += (float)v[s][q];
                    }
                }
            }
            #pragma unroll
            for (int s = 0; s < 4; s++) j[s] += m[s];
        }
        if (act) {
            #pragma unroll
            for (int s = 0; s < 4; s++) {
                int r = rb + s * 16;
                if (r < n) {
                    f16x8 o;
                    #pragma unroll
                    for (int q = 0; q < 8; q++) o[q] = (f16)acc[s][q];
                    *(f16x8*)(hi16 + (size_t)r * H + li * 8) = o;
                }
            }
        }
    } else {
        for (int t = tid; t < H * K_EXP; t += 256) ws[t] = cw[t];
        if (tid < K_EXP) bs[tid] = cb[tid];
        __syncthreads();
        int node = ((int)blockIdx.x - SPMM_BLOCKS) * 256 + tid;
        if (node >= n) return;
        float acc[K_EXP];
        #pragma unroll
        for (int k = 0; k < K_EXP; k++) acc[k] = bs[k];
        const f16* hr = h16 + (size_t)node * H;
        #pragma unroll 3
        for (int c8 = 0; c8 < 12; c8++) {
            f16x8 v = *(const f16x8*)(hr + c8 * 8);
            #pragma unroll
            for (int j = 0; j < 8; j++) {
                float hv = (float)v[j];
                int d = c8 * 8 + j;
                #pragma unroll
                for (int k = 0; k < K_EXP; k++) acc[k] += hv * ws[d * K_EXP + k];
            }
        }
        float mx = acc[0];
        #pragma unroll
        for (int k = 1; k < K_EXP; k++) mx = fmaxf(mx, acc[k]);
        float s = 0.f;
        #pragma unroll
        for (int k = 0; k < K_EXP; k++) { acc[k] = __expf(acc[k] - mx); s += acc[k]; }
        float inv = 1.f / s;
        #pragma unroll
        for (int k = 0; k < K_EXP; k++)
            zt[(size_t)k * N_NODES + node] = acc[k] * inv;
    }
}

// ---------------- fc0 via fp16 MFMA (writes fp16 h only) ----------------

#define FPAD 136

__global__ __launch_bounds__(256) void fc0_kernel(const float* __restrict__ x,
                                                  const f16* __restrict__ fc0t,
                                                  const float* __restrict__ b,
                                                  f16* __restrict__ h16, int n) {
    __shared__ f16 As[64 * FPAD];
    __shared__ f16 Ws[96 * FPAD];
    int tid = threadIdx.x;
    int l = tid & 63, w = tid >> 6;
    int quad = l >> 4, lc = l & 15;
    int row0 = blockIdx.x * 64;

    for (int t = tid; t < 2048; t += 256) {
        int m = t >> 5, c4 = (t & 31) * 4;
        int gr = row0 + m;
        float4 v = {0.f, 0.f, 0.f, 0.f};
        if (gr < n) v = *(const float4*)(x + (size_t)gr * DIN + c4);
        f16x4 h4 = {(f16)v.x, (f16)v.y, (f16)v.z, (f16)v.w};
        *(f16x4*)&As[m * FPAD + c4] = h4;
    }
    for (int t = tid; t < 1536; t += 256) {
        int o = t >> 4, c8 = (t & 15) * 8;
        *(f16x8*)&Ws[o * FPAD + c8] = *(const f16x8*)(fc0t + o * DIN + c8);
    }
    __syncthreads();

    f16x8 afr[4];
    #pragma unroll
    for (int ks = 0; ks < 4; ks++)
        afr[ks] = *(const f16x8*)&As[(16 * w + lc) * FPAD + ks * 32 + quad * 8];

    f32x4 acc[6] = {};
    #pragma unroll
    for (int ct = 0; ct < 6; ct++) {
        #pragma unroll
        for (int ks = 0; ks < 4; ks++) {
            f16x8 bfr = *(const f16x8*)&Ws[(ct * 16 + lc) * FPAD + ks * 32 + quad * 8];
            acc[ct] = __builtin_amdgcn_mfma_f32_16x16x32_f16(afr[ks], bfr, acc[ct], 0, 0, 0);
        }
    }

    int m0 = 16 * w + quad * 4;
    #pragma unroll
    for (int r = 0; r < 4; r++) {
        int gr = row0 + m0 + r;
        if (gr < n) {
            #pragma unroll
            for (int ct = 0; ct < 6; ct++) {
                int o = ct * 16 + lc;
                h16[(size_t)gr * H + o] = (f16)fmaxf(acc[ct][r] + b[o], 0.f);
            }
        }
    }
}

// ---------------- expert GEMM: LDS-staged fragment-linear weights ----------------

#define EG_STAGE 2
#define EG_HALFS (EG_STAGE * 9216)   // 18432 halfs = 36 KB

__global__ __launch_bounds__(256) void expert_gemm(const f16* __restrict__ hi16,
                                                   const f16* __restrict__ hin16,
                                                   const f16* __restrict__ wfrag, // [K][9216]
                                                   const float* __restrict__ zt,  // [K][N]
                                                   f16* __restrict__ hout16, int n) {
    __shared__ f16 Wl[EG_HALFS];
    int tid = threadIdx.x;
    int l = tid & 63, w = tid >> 6;
    int quad = l >> 4, lc = l & 15;
    int wrow0 = blockIdx.x * 64 + w * 16;

    f16x8 afr[3];
    #pragma unroll
    for (int ks = 0; ks < 3; ks++)
        afr[ks] = *(const f16x8*)(hi16 + (size_t)(wrow0 + lc) * H + ks * 32 + quad * 8);

    f32x4 acc[6] = {};

    for (int kb = 0; kb < K_EXP; kb += EG_STAGE) {
        __syncthreads();
        const f16* src = wfrag + (size_t)kb * 9216;
        for (int t = tid; t < EG_HALFS / 8; t += 256)
            *(f16x8*)&Wl[t * 8] = *(const f16x8*)(src + t * 8);
        __syncthreads();

        #pragma unroll
        for (int k2 = 0; k2 < EG_STAGE; k2++) {
            int k = kb + k2;
            f32x4 zf = *(const f32x4*)(zt + (size_t)k * N_NODES + wrow0 + quad * 4);
            #pragma unroll
            for (int ct = 0; ct < 6; ct++) {
                f16x8 b0 = *(const f16x8*)&Wl[k2 * 9216 + ct * 1536 + 0 * 512 + l * 8];
                f16x8 b1 = *(const f16x8*)&Wl[k2 * 9216 + ct * 1536 + 1 * 512 + l * 8];
                f16x8 b2 = *(const f16x8*)&Wl[k2 * 9216 + ct * 1536 + 2 * 512 + l * 8];
                f32x4 tmp = {};
                tmp = __builtin_amdgcn_mfma_f32_16x16x32_f16(afr[0], b0, tmp, 0, 0, 0);
                tmp = __builtin_amdgcn_mfma_f32_16x16x32_f16(afr[1], b1, tmp, 0, 0, 0);
                tmp = __builtin_amdgcn_mfma_f32_16x16x32_f16(afr[2], b2, tmp, 0, 0, 0);
                acc[ct] += zf * tmp;
            }
        }
    }

    #pragma unroll
    for (int r = 0; r < 4; r++) {
        int gr = wrow0 + quad * 4 + r;
        if (gr < n) {
            #pragma unroll
            for (int ct = 0; ct < 6; ct++) {
                int o = ct * 16 + lc;
                float v = fmaxf(acc[ct][r] + (float)hin16[(size_t)gr * H + o], 0.f);
                hout16[(size_t)gr * H + o] = (f16)v;
            }
        }
    }
}

// ---------------- fc1 via fp16 MFMA ----------------

#define APAD 104

__global__ __launch_bounds__(256) void fc1_kernel(const f16* __restrict__ h16,
                                                  const f16* __restrict__ fc1t,
                                                  const float* __restrict__ b,
                                                  float* __restrict__ out, int n) {
    __shared__ f16 As[64 * APAD];
    __shared__ f16 Ws[48 * APAD];
    int tid = threadIdx.x;
    int l = tid & 63, w = tid >> 6;
    int quad = l >> 4, lc = l & 15;
    int row0 = blockIdx.x * 64;

    for (int t = tid; t < 768; t += 256) {
        int m = t / 12, c8 = (t % 12) * 8;
        int gr = row0 + m;
        f16x8 v = {};
        if (gr < n) v = *(const f16x8*)(h16 + (size_t)gr * H + c8);
        *(f16x8*)&As[m * APAD + c8] = v;
    }
    for (int t = tid; t < 576; t += 256) {
        int o = t / 12, c8 = (t % 12) * 8;
        *(f16x8*)&Ws[o * APAD + c8] = *(const f16x8*)(fc1t + o * H + c8);
    }
    __syncthreads();

    f16x8 afr[3];
    #pragma unroll
    for (int ks = 0; ks < 3; ks++)
        afr[ks] = *(const f16x8*)&As[(16 * w + lc) * APAD + ks * 32 + quad * 8];

    f32x4 acc[3] = {};
    #pragma unroll
    for (int ct = 0; ct < 3; ct++) {
        #pragma unroll
        for (int ks = 0; ks < 3; ks++) {
            f16x8 bfr = *(const f16x8*)&Ws[(ct * 16 + lc) * APAD + ks * 32 + quad * 8];
            acc[ct] = __builtin_amdgcn_mfma_f32_16x16x32_f16(afr[ks], bfr, acc[ct], 0, 0, 0);
        }
    }

    int m0 = 16 * w + quad * 4;
    #pragma unroll
    for (int r = 0; r < 4; r++) {
        int gr = row0 + m0 + r;
        if (gr < n) {
            #pragma unroll
            for (int ct = 0; ct < 3; ct++) {
                int o = ct * 16 + lc;
                if (o < C_OUT)
                    out[(size_t)gr * C_OUT + o] = acc[ct][r] + b[o];
            }
        }
    }
}

// ---------------- launch ----------------

extern "C" void kernel_launch(void* const* d_in, const int* in_sizes, int n_in,
                              void* d_out, int out_size, void* d_ws, size_t ws_size,
                              hipStream_t stream) {
    const float* x      = (const float*)d_in[0];
    const int*   ei     = (const int*)d_in[1];
    const float* fc0_w  = (const float*)d_in[2];
    const float* fc0_b  = (const float*)d_in[3];
    const float* fc1_w  = (const float*)d_in[4];
    const float* fc1_b  = (const float*)d_in[5];
    const float* ctx_w  = (const float*)d_in[6];
    const float* ctx_b  = (const float*)d_in[7];
    const float* conv_w = (const float*)d_in[8];
    float* out = (float*)d_out;

    const size_t NH = (size_t)N_NODES * H;

    float* zbuf = (float*)d_ws;                          // [K][N] transposed
    f16*   h16a = (f16*)(zbuf + (size_t)N_NODES * K_EXP);
    f16*   h16b = h16a + NH;
    f16*   hi16 = h16b + NH;
    f16*   wfrag= hi16 + NH;
    f16*   fc0t = wfrag + CONV_TOT;
    f16*   fc1t = fc0t + FC0_TOT;
    int* rowptr = (int*)(fc1t + FC1_TOT);                // N+1
    int* deg    = rowptr + (N_NODES + 1);                // N
    int* csr    = deg + N_NODES;                         // E
    int* prank  = csr + N_EDGES;                         // E
    int* partial  = prank + N_EDGES;                     // 64

    const int* row = ei;
    const int* col = ei + N_EDGES;

    hipMemsetAsync(deg, 0, sizeof(int) * N_NODES, stream);

    count_p<<<(N_EDGES + 255) / 256, 256, 0, stream>>>(row, deg, prank, N_EDGES);
    int nsb = (N_NODES + 1023) / 1024;   // 49
    scanA<<<nsb, 1024, 0, stream>>>(deg, rowptr, partial, N_NODES);
    scanC<<<nsb, 1024, 0, stream>>>(rowptr, partial, nsb, N_NODES);
    scatter_store_xcd<<<1024, 256, 0, stream>>>(row, col, prank, rowptr, csr, N_EDGES);

    int ctotal = CONV_TOT + FC0_TOT + FC1_TOT;
    convert_all<<<(ctotal + 255) / 256, 256, 0, stream>>>(conv_w, fc0_w, fc1_w, wfrag, fc0t, fc1t);

    int gemm_grid = (N_NODES + 63) / 64;   // 782
    fc0_kernel<<<gemm_grid, 256, 0, stream>>>(x, fc0t, fc0_b, h16a, N_NODES);

    f16* hcur = h16a;
    f16* hnext = h16b;
    for (int i = 0; i < L_LAYERS; i++) {
        layer_pre<<<SPMM_BLOCKS + CTX_BLOCKS, 256, 0, stream>>>(
            hcur, rowptr, csr, hi16,
            ctx_w + (size_t)i * H * K_EXP, ctx_b + (size_t)i * K_EXP, zbuf, N_NODES);
        expert_gemm<<<gemm_grid, 256, 0, stream>>>(
            hi16, hcur, wfrag + (size_t)i * K_EXP * H * H, zbuf, hnext, N_NODES);
        f16* t = hcur; hcur = hnext; hnext = t;
    }
    fc1_kernel<<<gemm_grid, 256, 0, stream>>>(hcur, fc1t, fc1_b, out, N_NODES);
}

// Round 12
// 380.182 us; speedup vs baseline: 1.2009x; 1.2009x over previous
//
#include <hip/hip_runtime.h>

#define N_NODES 50000
#define N_EDGES 800000
#define DIN     128
#define H       96
#define K_EXP   8
#define L_LAYERS 4
#define C_OUT   40

#define GSZ 6250   // rows per XCD group = N_NODES/8

typedef _Float16 f16;
typedef f16 f16x2 __attribute__((ext_vector_type(2)));
typedef f16 f16x4 __attribute__((ext_vector_type(4)));
typedef f16 f16x8 __attribute__((ext_vector_type(8)));
typedef float f32x4 __attribute__((ext_vector_type(4)));

// ---------------- CSR build ----------------

__global__ __launch_bounds__(256) void count_p(const int* __restrict__ row,
                                               int* __restrict__ deg,
                                               int* __restrict__ p, int e) {
    int i = blockIdx.x * blockDim.x + threadIdx.x;
    if (i < e) p[i] = atomicAdd(&deg[row[i]], 1);
}

__global__ __launch_bounds__(1024) void scanA(const int* __restrict__ deg,
                                              int* __restrict__ rowptr,
                                              int* __restrict__ partial, int n) {
    __shared__ int wsum[16];
    int tid  = threadIdx.x;
    int lane = tid & 63, wid = tid >> 6;
    int idx = blockIdx.x * 1024 + tid;
    int v = (idx < n) ? deg[idx] : 0;
    int s = v;
    #pragma unroll
    for (int off = 1; off < 64; off <<= 1) {
        int t = __shfl_up(s, off, 64);
        if (lane >= off) s += t;
    }
    if (lane == 63) wsum[wid] = s;
    __syncthreads();
    if (wid == 0 && lane < 16) {
        int w = wsum[lane];
        #pragma unroll
        for (int off = 1; off < 16; off <<= 1) {
            int t = __shfl_up(w, off, 16);
            if (lane >= off) w += t;
        }
        wsum[lane] = w;
    }
    __syncthreads();
    int waveoff = (wid == 0) ? 0 : wsum[wid - 1];
    if (idx < n) rowptr[idx + 1] = waveoff + s;
    if (tid == 1023) partial[blockIdx.x] = waveoff + s;
}

// scanC with folded block-offset reduction: each block sums partial[0..bid-1]
__global__ __launch_bounds__(1024) void scanC(int* __restrict__ rowptr,
                                              const int* __restrict__ partial,
                                              int nb, int n) {
    __shared__ int boff_s;
    int tid = threadIdx.x;
    if (tid < 64) {
        int v = (tid < nb && tid < (int)blockIdx.x) ? partial[tid] : 0;
        #pragma unroll
        for (int off = 32; off >= 1; off >>= 1) v += __shfl_xor(v, off, 64);
        if (tid == 0) boff_s = v;
    }
    __syncthreads();
    int boff = boff_s;
    int idx = blockIdx.x * 1024 + tid;
    if (idx == 0) rowptr[0] = 0;
    if (idx < n) rowptr[idx + 1] += boff;
}

__global__ __launch_bounds__(256) void scatter_store_xcd(const int* __restrict__ row,
                                                         const int* __restrict__ col,
                                                         const int* __restrict__ p,
                                                         const int* __restrict__ rowptr,
                                                         int* __restrict__ csr, int e) {
    int g = blockIdx.x & 7;
    int rlo = g * GSZ, rhi = rlo + GSZ;
    int stride = (gridDim.x >> 3) * 256;
    for (int i = (blockIdx.x >> 3) * 256 + threadIdx.x; i < e; i += stride) {
        int r = row[i];
        if (r >= rlo && r < rhi)
            csr[rowptr[r] + p[i]] = col[i];
    }
}

// ---------------- weight conversion ----------------

#define CONV_TOT (L_LAYERS * K_EXP * H * H)   // 294912
#define FC0_TOT  (DIN * H)                    // 12288
#define FC1_TOT  (48 * H)                     // 4608

__global__ void convert_all(const float* __restrict__ conv_w,
                            const float* __restrict__ fc0_w,
                            const float* __restrict__ fc1_w,
                            f16* __restrict__ wfrag, f16* __restrict__ fc0t,
                            f16* __restrict__ fc1t) {
    int i = blockIdx.x * blockDim.x + threadIdx.x;
    if (i < CONV_TOT) {
        int o = i % H;
        int t = i / H;
        int d = t % H;
        int lk = t / H;
        int ct = o >> 4, lc = o & 15;
        int ks = d >> 5, quad = (d >> 3) & 3, j = d & 7;
        wfrag[(size_t)lk * 9216 + ct * 1536 + ks * 512 + (quad * 16 + lc) * 8 + j] =
            (f16)conv_w[i];
    } else if (i < CONV_TOT + FC0_TOT) {
        int j = i - CONV_TOT;      // j = d*96+o
        int o = j % H, d = j / H;
        fc0t[o * DIN + d] = (f16)fc0_w[j];
    } else if (i < CONV_TOT + FC0_TOT + FC1_TOT) {
        int j = i - CONV_TOT - FC0_TOT;  // target [o][d]
        int o = j / H, d = j % H;
        fc1t[j] = (o < C_OUT) ? (f16)fc1_w[d * C_OUT + o] : (f16)0.f;
    }
}

// ---------------- fused per-layer pre-pass: spmm + ctx softmax ----------------
// spmm: 32 rows/block, 16 lanes/group; each group interleaves TWO independent
// rows (r, r+16), and the edge loop is unrolled x2 -> up to 4 independent
// gather loads in flight per lane, without shrinking the grid (1563 blocks).

#define SPMM_BLOCKS ((N_NODES + 31) / 32)    // 1563
#define CTX_BLOCKS  ((N_NODES + 255) / 256)  // 196

__global__ __launch_bounds__(256) void layer_pre(const f16* __restrict__ h16,
                                                 const int* __restrict__ rowptr,
                                                 const int* __restrict__ csr,
                                                 f16* __restrict__ hi16,
                                                 const float* __restrict__ cw,
                                                 const float* __restrict__ cb,
                                                 float* __restrict__ zt, int n) {
    __shared__ float ws[H * K_EXP];
    __shared__ float bs[K_EXP];
    int tid = threadIdx.x;
    if ((int)blockIdx.x < SPMM_BLOCKS) {
        int r0 = blockIdx.x * 32 + (tid >> 4);   // row A
        int r1 = r0 + 16;                        // row B
        int li = tid & 15;
        if (r0 >= n) return;
        int j0 = rowptr[r0], e0 = rowptr[r0 + 1];
        int j1 = 0, e1 = 0;
        if (r1 < n) { j1 = rowptr[r1]; e1 = rowptr[r1 + 1]; }
        bool act = li < 12;
        float accA[8] = {}, accB[8] = {};
        for (;;) {
            int m0 = e0 - j0; if (m0 > 16) m0 = 16;
            int m1 = e1 - j1; if (m1 > 16) m1 = 16;
            if (m0 <= 0 && m1 <= 0) break;
            int c0 = 0, c1 = 0;
            if (li < m0) c0 = csr[j0 + li];
            if (li < m1) c1 = csr[j1 + li];
            int mm = m0 > m1 ? m0 : m1;
            int t = 0;
            // x2 unrolled: 4 independent gathers in flight
            for (; t + 2 <= mm; t += 2) {
                int cc0a = __shfl(c0, t, 16),     cc1a = __shfl(c1, t, 16);
                int cc0b = __shfl(c0, t + 1, 16), cc1b = __shfl(c1, t + 1, 16);
                bool a0a = act && (t < m0),     a1a = act && (t < m1);
                bool a0b = act && (t + 1 < m0), a1b = act && (t + 1 < m1);
                f16x8 v0a = {}, v1a = {}, v0b = {}, v1b = {};
                if (a0a) v0a = *(const f16x8*)(h16 + (size_t)cc0a * H + li * 8);
                if (a1a) v1a = *(const f16x8*)(h16 + (size_t)cc1a * H + li * 8);
                if (a0b) v0b = *(const f16x8*)(h16 + (size_t)cc0b * H + li * 8);
                if (a1b) v1b = *(const f16x8*)(h16 + (size_t)cc1b * H + li * 8);
                if (a0a) {
                    #pragma unroll
                    for (int q = 0; q < 8; q++) accA[q] += (float)v0a[q];
                }
                if (a1a) {
                    #pragma unroll
                    for (int q = 0; q < 8; q++) accB[q] += (float)v1a[q];
                }
                if (a0b) {
                    #pragma unroll
                    for (int q = 0; q < 8; q++) accA[q] += (float)v0b[q];
                }
                if (a1b) {
                    #pragma unroll
                    for (int q = 0; q < 8; q++) accB[q] += (float)v1b[q];
                }
            }
            if (t < mm) {
                int cc0 = __shfl(c0, t, 16), cc1 = __shfl(c1, t, 16);
                bool a0 = act && (t < m0), a1 = act && (t < m1);
                f16x8 v0 = {}, v1 = {};
                if (a0) v0 = *(const f16x8*)(h16 + (size_t)cc0 * H + li * 8);
                if (a1) v1 = *(const f16x8*)(h16 + (size_t)cc1 * H + li * 8);
                if (a0) {
                    #pragma unroll
                    for (int q = 0; q < 8; q++) accA[q] += (float)v0[q];
                }
                if (a1) {
                    #pragma unroll
                    for (int q = 0; q < 8; q++) accB[q] += (float)v1[q];
                }
            }
            j0 += m0; j1 += m1;
        }
        if (act) {
            f16x8 oA;
            #pragma unroll
            for (int q = 0; q < 8; q++) oA[q] = (f16)accA[q];
            *(f16x8*)(hi16 + (size_t)r0 * H + li * 8) = oA;
            if (r1 < n) {
                f16x8 oB;
                #pragma unroll
                for (int q = 0; q < 8; q++) oB[q] = (f16)accB[q];
                *(f16x8*)(hi16 + (size_t)r1 * H + li * 8) = oB;
            }
        }
    } else {
        for (int t = tid; t < H * K_EXP; t += 256) ws[t] = cw[t];
        if (tid < K_EXP) bs[tid] = cb[tid];
        __syncthreads();
        int node = ((int)blockIdx.x - SPMM_BLOCKS) * 256 + tid;
        if (node >= n) return;
        float acc[K_EXP];
        #pragma unroll
        for (int k = 0; k < K_EXP; k++) acc[k] = bs[k];
        const f16* hr = h16 + (size_t)node * H;
        #pragma unroll 3
        for (int c8 = 0; c8 < 12; c8++) {
            f16x8 v = *(const f16x8*)(hr + c8 * 8);
            #pragma unroll
            for (int j = 0; j < 8; j++) {
                float hv = (float)v[j];
                int d = c8 * 8 + j;
                #pragma unroll
                for (int k = 0; k < K_EXP; k++) acc[k] += hv * ws[d * K_EXP + k];
            }
        }
        float mx = acc[0];
        #pragma unroll
        for (int k = 1; k < K_EXP; k++) mx = fmaxf(mx, acc[k]);
        float s = 0.f;
        #pragma unroll
        for (int k = 0; k < K_EXP; k++) { acc[k] = __expf(acc[k] - mx); s += acc[k]; }
        float inv = 1.f / s;
        #pragma unroll
        for (int k = 0; k < K_EXP; k++)
            zt[(size_t)k * N_NODES + node] = acc[k] * inv;
    }
}

// ---------------- fc0 via fp16 MFMA (writes fp16 h only) ----------------

#define FPAD 136

__global__ __launch_bounds__(256) void fc0_kernel(const float* __restrict__ x,
                                                  const f16* __restrict__ fc0t,
                                                  const float* __restrict__ b,
                                                  f16* __restrict__ h16, int n) {
    __shared__ f16 As[64 * FPAD];
    __shared__ f16 Ws[96 * FPAD];
    int tid = threadIdx.x;
    int l = tid & 63, w = tid >> 6;
    int quad = l >> 4, lc = l & 15;
    int row0 = blockIdx.x * 64;

    for (int t = tid; t < 2048; t += 256) {
        int m = t >> 5, c4 = (t & 31) * 4;
        int gr = row0 + m;
        float4 v = {0.f, 0.f, 0.f, 0.f};
        if (gr < n) v = *(const float4*)(x + (size_t)gr * DIN + c4);
        f16x4 h4 = {(f16)v.x, (f16)v.y, (f16)v.z, (f16)v.w};
        *(f16x4*)&As[m * FPAD + c4] = h4;
    }
    for (int t = tid; t < 1536; t += 256) {
        int o = t >> 4, c8 = (t & 15) * 8;
        *(f16x8*)&Ws[o * FPAD + c8] = *(const f16x8*)(fc0t + o * DIN + c8);
    }
    __syncthreads();

    f16x8 afr[4];
    #pragma unroll
    for (int ks = 0; ks < 4; ks++)
        afr[ks] = *(const f16x8*)&As[(16 * w + lc) * FPAD + ks * 32 + quad * 8];

    f32x4 acc[6] = {};
    #pragma unroll
    for (int ct = 0; ct < 6; ct++) {
        #pragma unroll
        for (int ks = 0; ks < 4; ks++) {
            f16x8 bfr = *(const f16x8*)&Ws[(ct * 16 + lc) * FPAD + ks * 32 + quad * 8];
            acc[ct] = __builtin_amdgcn_mfma_f32_16x16x32_f16(afr[ks], bfr, acc[ct], 0, 0, 0);
        }
    }

    int m0 = 16 * w + quad * 4;
    #pragma unroll
    for (int r = 0; r < 4; r++) {
        int gr = row0 + m0 + r;
        if (gr < n) {
            #pragma unroll
            for (int ct = 0; ct < 6; ct++) {
                int o = ct * 16 + lc;
                h16[(size_t)gr * H + o] = (f16)fmaxf(acc[ct][r] + b[o], 0.f);
            }
        }
    }
}

// ---------------- expert GEMM: LDS-staged fragment-linear weights ----------------

#define EG_STAGE 2
#define EG_HALFS (EG_STAGE * 9216)   // 18432 halfs = 36 KB

__global__ __launch_bounds__(256) void expert_gemm(const f16* __restrict__ hi16,
                                                   const f16* __restrict__ hin16,
                                                   const f16* __restrict__ wfrag, // [K][9216]
                                                   const float* __restrict__ zt,  // [K][N]
                                                   f16* __restrict__ hout16, int n) {
    __shared__ f16 Wl[EG_HALFS];
    int tid = threadIdx.x;
    int l = tid & 63, w = tid >> 6;
    int quad = l >> 4, lc = l & 15;
    int wrow0 = blockIdx.x * 64 + w * 16;

    f16x8 afr[3];
    #pragma unroll
    for (int ks = 0; ks < 3; ks++)
        afr[ks] = *(const f16x8*)(hi16 + (size_t)(wrow0 + lc) * H + ks * 32 + quad * 8);

    f32x4 acc[6] = {};

    for (int kb = 0; kb < K_EXP; kb += EG_STAGE) {
        __syncthreads();
        const f16* src = wfrag + (size_t)kb * 9216;
        for (int t = tid; t < EG_HALFS / 8; t += 256)
            *(f16x8*)&Wl[t * 8] = *(const f16x8*)(src + t * 8);
        __syncthreads();

        #pragma unroll
        for (int k2 = 0; k2 < EG_STAGE; k2++) {
            int k = kb + k2;
            f32x4 zf = *(const f32x4*)(zt + (size_t)k * N_NODES + wrow0 + quad * 4);
            #pragma unroll
            for (int ct = 0; ct < 6; ct++) {
                f16x8 b0 = *(const f16x8*)&Wl[k2 * 9216 + ct * 1536 + 0 * 512 + l * 8];
                f16x8 b1 = *(const f16x8*)&Wl[k2 * 9216 + ct * 1536 + 1 * 512 + l * 8];
                f16x8 b2 = *(const f16x8*)&Wl[k2 * 9216 + ct * 1536 + 2 * 512 + l * 8];
                f32x4 tmp = {};
                tmp = __builtin_amdgcn_mfma_f32_16x16x32_f16(afr[0], b0, tmp, 0, 0, 0);
                tmp = __builtin_amdgcn_mfma_f32_16x16x32_f16(afr[1], b1, tmp, 0, 0, 0);
                tmp = __builtin_amdgcn_mfma_f32_16x16x32_f16(afr[2], b2, tmp, 0, 0, 0);
                acc[ct] += zf * tmp;
            }
        }
    }

    #pragma unroll
    for (int r = 0; r < 4; r++) {
        int gr = wrow0 + quad * 4 + r;
        if (gr < n) {
            #pragma unroll
            for (int ct = 0; ct < 6; ct++) {
                int o = ct * 16 + lc;
                float v = fmaxf(acc[ct][r] + (float)hin16[(size_t)gr * H + o], 0.f);
                hout16[(size_t)gr * H + o] = (f16)v;
            }
        }
    }
}

// ---------------- fc1 via fp16 MFMA ----------------

#define APAD 104

__global__ __launch_bounds__(256) void fc1_kernel(const f16* __restrict__ h16,
                                                  const f16* __restrict__ fc1t,
                                                  const float* __restrict__ b,
                                                  float* __restrict__ out, int n) {
    __shared__ f16 As[64 * APAD];
    __shared__ f16 Ws[48 * APAD];
    int tid = threadIdx.x;
    int l = tid & 63, w = tid >> 6;
    int quad = l >> 4, lc = l & 15;
    int row0 = blockIdx.x * 64;

    for (int t = tid; t < 768; t += 256) {
        int m = t / 12, c8 = (t % 12) * 8;
        int gr = row0 + m;
        f16x8 v = {};
        if (gr < n) v = *(const f16x8*)(h16 + (size_t)gr * H + c8);
        *(f16x8*)&As[m * APAD + c8] = v;
    }
    for (int t = tid; t < 576; t += 256) {
        int o = t / 12, c8 = (t % 12) * 8;
        *(f16x8*)&Ws[o * APAD + c8] = *(const f16x8*)(fc1t + o * H + c8);
    }
    __syncthreads();

    f16x8 afr[3];
    #pragma unroll
    for (int ks = 0; ks < 3; ks++)
        afr[ks] = *(const f16x8*)&As[(16 * w + lc) * APAD + ks * 32 + quad * 8];

    f32x4 acc[3] = {};
    #pragma unroll
    for (int ct = 0; ct < 3; ct++) {
        #pragma unroll
        for (int ks = 0; ks < 3; ks++) {
            f16x8 bfr = *(const f16x8*)&Ws[(ct * 16 + lc) * APAD + ks * 32 + quad * 8];
            acc[ct] = __builtin_amdgcn_mfma_f32_16x16x32_f16(afr[ks], bfr, acc[ct], 0, 0, 0);
        }
    }

    int m0 = 16 * w + quad * 4;
    #pragma unroll
    for (int r = 0; r < 4; r++) {
        int gr = row0 + m0 + r;
        if (gr < n) {
            #pragma unroll
            for (int ct = 0; ct < 3; ct++) {
                int o = ct * 16 + lc;
                if (o < C_OUT)
                    out[(size_t)gr * C_OUT + o] = acc[ct][r] + b[o];
            }
        }
    }
}

// ---------------- launch ----------------

extern "C" void kernel_launch(void* const* d_in, const int* in_sizes, int n_in,
                              void* d_out, int out_size, void* d_ws, size_t ws_size,
                              hipStream_t stream) {
    const float* x      = (const float*)d_in[0];
    const int*   ei     = (const int*)d_in[1];
    const float* fc0_w  = (const float*)d_in[2];
    const float* fc0_b  = (const float*)d_in[3];
    const float* fc1_w  = (const float*)d_in[4];
    const float* fc1_b  = (const float*)d_in[5];
    const float* ctx_w  = (const float*)d_in[6];
    const float* ctx_b  = (const float*)d_in[7];
    const float* conv_w = (const float*)d_in[8];
    float* out = (float*)d_out;

    const size_t NH = (size_t)N_NODES * H;

    float* zbuf = (float*)d_ws;                          // [K][N] transposed
    f16*   h16a = (f16*)(zbuf + (size_t)N_NODES * K_EXP);
    f16*   h16b = h16a + NH;
    f16*   hi16 = h16b + NH;
    f16*   wfrag= hi16 + NH;
    f16*   fc0t = wfrag + CONV_TOT;
    f16*   fc1t = fc0t + FC0_TOT;
    int* rowptr = (int*)(fc1t + FC1_TOT);                // N+1
    int* deg    = rowptr + (N_NODES + 1);                // N
    int* csr    = deg + N_NODES;                         // E
    int* prank  = csr + N_EDGES;                         // E
    int* partial  = prank + N_EDGES;                     // 64

    const int* row = ei;
    const int* col = ei + N_EDGES;

    hipMemsetAsync(deg, 0, sizeof(int) * N_NODES, stream);

    count_p<<<(N_EDGES + 255) / 256, 256, 0, stream>>>(row, deg, prank, N_EDGES);
    int nsb = (N_NODES + 1023) / 1024;   // 49
    scanA<<<nsb, 1024, 0, stream>>>(deg, rowptr, partial, N_NODES);
    scanC<<<nsb, 1024, 0, stream>>>(rowptr, partial, nsb, N_NODES);
    scatter_store_xcd<<<1024, 256, 0, stream>>>(row, col, prank, rowptr, csr, N_EDGES);

    int ctotal = CONV_TOT + FC0_TOT + FC1_TOT;
    convert_all<<<(ctotal + 255) / 256, 256, 0, stream>>>(conv_w, fc0_w, fc1_w, wfrag, fc0t, fc1t);

    int gemm_grid = (N_NODES + 63) / 64;   // 782
    fc0_kernel<<<gemm_grid, 256, 0, stream>>>(x, fc0t, fc0_b, h16a, N_NODES);

    f16* hcur = h16a;
    f16* hnext = h16b;
    for (int i = 0; i < L_LAYERS; i++) {
        layer_pre<<<SPMM_BLOCKS + CTX_BLOCKS, 256, 0, stream>>>(
            hcur, rowptr, csr, hi16,
            ctx_w + (size_t)i * H * K_EXP, ctx_b + (size_t)i * K_EXP, zbuf, N_NODES);
        expert_gemm<<<gemm_grid, 256, 0, stream>>>(
            hi16, hcur, wfrag + (size_t)i * K_EXP * H * H, zbuf, hnext, N_NODES);
        f16* t = hcur; hcur = hnext; hnext = t;
    }
    fc1_kernel<<<gemm_grid, 256, 0, stream>>>(hcur, fc1t, fc1_b, out, N_NODES);
}